// Round 14
// baseline (256.538 us; speedup 1.0000x reference)
//
#include <hip/hip_runtime.h>
#include <hip/hip_bf16.h>
#include <math.h>

typedef float f32x4 __attribute__((ext_vector_type(4)));
typedef _Float16 f16x8 __attribute__((ext_vector_type(8)));
typedef _Float16 f16x4 __attribute__((ext_vector_type(4)));

#define TT 1024
#define DD 1024
#define QS 4608   // mega row stride (f16): [qkv 3072 | lines 512 | mv 1024]

typedef __attribute__((address_space(1))) const void gas_void;
typedef __attribute__((address_space(3))) void las_void;
static __device__ __forceinline__ void gl_lds16(const void* g, void* l) {
  __builtin_amdgcn_global_load_lds((gas_void*)g, (las_void*)l, 16, 0, 0);
}

// ============ f16 GEMM: 128x128 tile, 512 thr (8 waves 4x2), BK=32, 4-slot vmcnt ring ============
// A[M][K] f16, Wt[N][K] f16 (pre-transposed). C = A·Wt^T (+bias)(+gelu).
// LDS linear [row][4 chunks of 8 f16]; content pre-swizzled: pos(row,q) holds chunk q^((row>>1)&3).
// 4-slot ring (64KB): stage(kt+3) issued after barrier of iter kt -> 3 iterations of latency cover;
// steady-state wait = counted vmcnt(4) (stages kt+1,kt+2 stay in flight across the barrier).
// mode: 1 = store f16 | 2 = atomicAdd f32 (pre-initialized buffer; bias ignored) | 3 = store f32 + bias + residual
__global__ __launch_bounds__(512) void gemm_t16(
    const _Float16* __restrict__ A, const _Float16* __restrict__ Wt,
    const float* __restrict__ bias, const float* __restrict__ residual,
    void* __restrict__ Cv, int N, int K, int act, int gx, int mode, int ktiles) {
  __shared__ __align__(16) _Float16 As[4][4096];   // 128x32 each
  __shared__ __align__(16) _Float16 Bs[4][4096];
  const int tid = threadIdx.x;
  const int lane = tid & 63;
  const int wid = tid >> 6;                 // 0..7
  const int wr = wid >> 1, wc = wid & 1;    // 4x2 wave grid; wave tile 32r x 64c
  const int g = lane >> 4, l16 = lane & 15;
  const int cpx = gridDim.x >> 3;
  const int wg = (blockIdx.x & 7) * cpx + (blockIdx.x >> 3);   // XCD swizzle
  const int row0 = (wg / gx) * 128, col0 = (wg % gx) * 128;
  const int kbeg = blockIdx.y * ktiles * 32;

  f32x4 acc[2][4];
#pragma unroll
  for (int m = 0; m < 2; ++m)
#pragma unroll
    for (int n = 0; n < 4; ++n) acc[m][n] = (f32x4){0.f, 0.f, 0.f, 0.f};

  const int srow = tid >> 2;
  const int goff = ((tid & 3) ^ ((srow >> 1) & 3)) << 3;
  const _Float16* agp = A + (size_t)(row0 + srow) * K + kbeg + goff;
  const _Float16* bgp = Wt + (size_t)(col0 + srow) * K + kbeg + goff;
  const int ldst = tid * 16;   // byte offset in tile

  const int prm = (l16 >> 1) & 3;  // fragment-read chunk perm

  // prologue: stage tiles 0..2 into slots 0..2
  gl_lds16(agp, (char*)As[0] + ldst);
  gl_lds16(bgp, (char*)Bs[0] + ldst);
  if (1 < ktiles) {
    gl_lds16(agp + 32, (char*)As[1] + ldst);
    gl_lds16(bgp + 32, (char*)Bs[1] + ldst);
  }
  if (2 < ktiles) {
    gl_lds16(agp + 64, (char*)As[2] + ldst);
    gl_lds16(bgp + 64, (char*)Bs[2] + ldst);
  }

  for (int kt = 0; kt < ktiles; ++kt) {
    const int rem = ktiles - 1 - kt;
    if (rem >= 2)      asm volatile("s_waitcnt vmcnt(4)" ::: "memory");
    else if (rem == 1) asm volatile("s_waitcnt vmcnt(2)" ::: "memory");
    else               asm volatile("s_waitcnt vmcnt(0)" ::: "memory");
    __builtin_amdgcn_s_barrier();        // raw barrier: does NOT drain vmcnt
    __builtin_amdgcn_sched_barrier(0);   // no ds_read hoisted above the barrier
    if (kt + 3 < ktiles) {               // slot (kt+3)&3 == (kt-1)&3: fully consumed pre-barrier
      const int kp = (kt + 3) * 32;
      const int b4 = (kt + 3) & 3;
      gl_lds16(agp + kp, (char*)As[b4] + ldst);
      gl_lds16(bgp + kp, (char*)Bs[b4] + ldst);
    }
    const int cs = kt & 3;
    f16x8 af[2], bf[4];
#pragma unroll
    for (int m = 0; m < 2; ++m) {
      const int r = wr * 32 + m * 16 + l16;
      af[m] = *(const f16x8*)(As[cs] + r * 32 + ((g ^ prm) << 3));
    }
#pragma unroll
    for (int n = 0; n < 4; ++n) {
      const int c = wc * 64 + n * 16 + l16;
      bf[n] = *(const f16x8*)(Bs[cs] + c * 32 + ((g ^ prm) << 3));
    }
#pragma unroll
    for (int m = 0; m < 2; ++m)
#pragma unroll
      for (int n = 0; n < 4; ++n)
        acc[m][n] = __builtin_amdgcn_mfma_f32_16x16x32_f16(af[m], bf[n], acc[m][n], 0, 0, 0);
  }
#pragma unroll
  for (int m = 0; m < 2; ++m) {
#pragma unroll
    for (int n = 0; n < 4; ++n) {
      const int col = col0 + wc * 64 + n * 16 + l16;
      const float bv = (mode != 2 && bias) ? bias[col] : 0.f;
#pragma unroll
      for (int rg = 0; rg < 4; ++rg) {
        const int row = row0 + wr * 32 + m * 16 + g * 4 + rg;
        const size_t off = (size_t)row * N + col;
        float v = acc[m][n][rg] + bv;
        if (act == 1) v = 0.5f * v * (1.f + erff(v * 0.70710678118654752f));
        if (mode == 2) atomicAdd(&((float*)Cv)[off], v);
        else if (mode == 3) ((float*)Cv)[off] = v + residual[off];
        else ((_Float16*)Cv)[off] = (_Float16)v;
      }
    }
  }
}

// ============ fused weight prep: megaT + 3 transposes + biases + gm zero in ONE dispatch ============
static __device__ __forceinline__ void trans_tile(const float* __restrict__ W,
    _Float16* __restrict__ WT, int K, int N, int n0, int k0, int tid) {
  __shared__ float tile[64][65];
  const int tn = tid & 63, tk4 = tid >> 6;
#pragma unroll
  for (int it = 0; it < 16; ++it) {
    const int k = k0 + it * 4 + tk4;
    tile[tn][it * 4 + tk4] = W[(size_t)k * N + n0 + tn];
  }
  __syncthreads();
  const int on = tid >> 2, ok = tid & 3;
  f16x8 a, b;
#pragma unroll
  for (int j = 0; j < 8; ++j) {
    a[j] = (_Float16)tile[on][ok * 16 + j];
    b[j] = (_Float16)tile[on][ok * 16 + 8 + j];
  }
  _Float16* dst = WT + (size_t)(n0 + on) * K + k0 + ok * 16;
  *(f16x8*)dst = a;
  *(f16x8*)(dst + 8) = b;
}

__global__ __launch_bounds__(256) void prep_all(
    const float* __restrict__ Wqkv, const float* __restrict__ W1w, const float* __restrict__ W2w,
    const float* __restrict__ W1r, const float* __restrict__ W2r, const float* __restrict__ Wmg,
    const float* __restrict__ Wmv, const float* __restrict__ Wout, const float* __restrict__ Wfc,
    const float* __restrict__ Wproj, const float* __restrict__ bqkv, const float* __restrict__ bmg,
    const float* __restrict__ bmv, _Float16* __restrict__ WmT, _Float16* __restrict__ WoutT,
    _Float16* __restrict__ WfcT, _Float16* __restrict__ WprojT, float* __restrict__ bm,
    float* __restrict__ gm) {
  const int id = blockIdx.x;
  const int tid = threadIdx.x;
  if (id < 1152) {                      // megaT gather-transpose: 72 n-tiles x 16 k-tiles
    __shared__ float tile[64][65];
    const int n0 = (id % 72) * 64, k0 = (id / 72) * 64;
    const int tn = tid & 63, tk4 = tid >> 6;
#pragma unroll
    for (int it = 0; it < 16; ++it) {
      const int k = k0 + it * 4 + tk4;
      const int n = n0 + tn;
      float v;
      if (n < 3072) v = Wqkv[(size_t)k * 3072 + n];
      else if (n < 3136) v = W1w[k * 64 + n - 3072];
      else if (n < 3200) v = W2w[k * 64 + n - 3136];
      else if (n < 3264) v = W1r[k * 64 + n - 3200];
      else if (n < 3328) v = W2r[k * 64 + n - 3264];
      else if (n < 3344) v = Wmg[k * 16 + n - 3328];
      else if (n < 3584) v = 0.f;
      else v = Wmv[(size_t)k * 1024 + n - 3584];
      tile[tn][it * 4 + tk4] = v;
    }
    __syncthreads();
    const int on = tid >> 2, ok = tid & 3;
    f16x8 a, b;
#pragma unroll
    for (int j = 0; j < 8; ++j) {
      a[j] = (_Float16)tile[on][ok * 16 + j];
      b[j] = (_Float16)tile[on][ok * 16 + 8 + j];
    }
    _Float16* dst = WmT + (size_t)(n0 + on) * 1024 + k0 + ok * 16;
    *(f16x8*)dst = a;
    *(f16x8*)(dst + 8) = b;
  } else if (id < 1408) {               // WoutT: 16 x 16
    const int i2 = id - 1152;
    trans_tile(Wout, WoutT, 1024, 1024, (i2 % 16) * 64, (i2 / 16) * 64, tid);
  } else if (id < 2432) {               // WfcT: 64 x 16
    const int i2 = id - 1408;
    trans_tile(Wfc, WfcT, 1024, 4096, (i2 % 64) * 64, (i2 / 64) * 64, tid);
  } else if (id < 3456) {               // WprojT: 16 x 64
    const int i2 = id - 2432;
    trans_tile(Wproj, WprojT, 4096, 1024, (i2 % 16) * 64, (i2 / 16) * 64, tid);
  } else if (id < 3474) {               // bm: 18 blocks x 256
    const int col = (id - 3456) * 256 + tid;
    if (col < 4608) {
      float b = 0.f;
      if (col < 3072) b = bqkv[col];
      else if (col >= 3328 && col < 3344) b = bmg[col - 3328];
      else if (col >= 3584) b = bmv[col - 3584];
      bm[col] = b;
    }
  } else {                              // gm zero: 8 blocks x 256 = 2048
    gm[(id - 3474) * 256 + tid] = 0.f;
  }
}

// ============ LayerNorm -> f16 ============
__global__ __launch_bounds__(256) void ln16(const float* __restrict__ in,
    const float* __restrict__ gw, const float* __restrict__ bw, _Float16* __restrict__ out) {
  const int row = blockIdx.x, tid = threadIdx.x;
  const float* x = in + (size_t)row * DD;
  const float4 v = *(const float4*)(x + tid * 4);
  float s = v.x + v.y + v.z + v.w;
  float sq = v.x * v.x + v.y * v.y + v.z * v.z + v.w * v.w;
#pragma unroll
  for (int off = 32; off >= 1; off >>= 1) { s += __shfl_xor(s, off); sq += __shfl_xor(sq, off); }
  __shared__ float red[8];
  const int lane = tid & 63, wv = tid >> 6;
  if (lane == 0) { red[wv] = s; red[4 + wv] = sq; }
  __syncthreads();
  s = red[0] + red[1] + red[2] + red[3];
  sq = red[4] + red[5] + red[6] + red[7];
  const float mean = s * (1.f / 1024.f);
  const float var = sq * (1.f / 1024.f) - mean * mean;
  const float rstd = rsqrtf(var + 1e-5f);
  const float4 g4 = *(const float4*)(gw + tid * 4);
  const float4 b4 = *(const float4*)(bw + tid * 4);
  f16x4 o;
  o[0] = (_Float16)((v.x - mean) * rstd * g4.x + b4.x);
  o[1] = (_Float16)((v.y - mean) * rstd * g4.y + b4.y);
  o[2] = (_Float16)((v.z - mean) * rstd * g4.z + b4.z);
  o[3] = (_Float16)((v.w - mean) * rstd * g4.w + b4.w);
  *(f16x4*)(out + (size_t)row * DD + tid * 4) = o;
}

// ============ MFMA f16 causal flash attention, PAIRED q-tiles (qt=p and qt=15-p) ============
static __device__ __forceinline__ int swzA(int row, int k) {
  return row * 64 + ((((k >> 3) ^ row) & 7) << 3) + (k & 7);
}
static __device__ __forceinline__ int swzV(int row, int k) {
  return row * 64 + ((((k >> 3) ^ row ^ (row >> 3)) & 7) << 3) + (k & 7);
}

static __device__ __forceinline__ void attn_step(
    const f16x8* qf, f32x4* oacc, float* m, float* l,
    const _Float16* Kl, const _Float16* Vt, _Float16* Plw,
    bool diag, int wq, int g, int l16) {
  f32x4 s[4];
#pragma unroll
  for (int n = 0; n < 4; ++n) s[n] = (f32x4){0.f, 0.f, 0.f, 0.f};
#pragma unroll
  for (int ks = 0; ks < 2; ++ks) {
    f16x8 kf[4];
#pragma unroll
    for (int n = 0; n < 4; ++n) kf[n] = *(const f16x8*)(Kl + swzA(n * 16 + l16, ks * 32 + g * 8));
#pragma unroll
    for (int n = 0; n < 4; ++n)
      s[n] = __builtin_amdgcn_mfma_f32_16x16x32_f16(qf[ks], kf[n], s[n], 0, 0, 0);
  }
  if (diag) {
    const int rloc = wq * 16 + g * 4;
#pragma unroll
    for (int n = 0; n < 4; ++n) {
      const int cloc = n * 16 + l16;
#pragma unroll
      for (int reg = 0; reg < 4; ++reg)
        if (cloc > rloc + reg) s[n][reg] = -INFINITY;
    }
  }
  float f[4];
#pragma unroll
  for (int reg = 0; reg < 4; ++reg) {
    float t = fmaxf(fmaxf(s[0][reg], s[1][reg]), fmaxf(s[2][reg], s[3][reg]));
#pragma unroll
    for (int off = 1; off < 16; off <<= 1) t = fmaxf(t, __shfl_xor(t, off));
    const float nm = fmaxf(m[reg], t);
    f[reg] = __expf(m[reg] - nm);
    m[reg] = nm;
  }
  float rs[4] = {0.f, 0.f, 0.f, 0.f};
#pragma unroll
  for (int n = 0; n < 4; ++n) {
#pragma unroll
    for (int reg = 0; reg < 4; ++reg) {
      const float p = __expf(s[n][reg] - m[reg]);
      rs[reg] += p;
      Plw[swzA(g * 4 + reg, n * 16 + l16)] = (_Float16)p;
    }
  }
#pragma unroll
  for (int reg = 0; reg < 4; ++reg) {
    float t = rs[reg];
#pragma unroll
    for (int off = 1; off < 16; off <<= 1) t += __shfl_xor(t, off);
    l[reg] = l[reg] * f[reg] + t;
  }
#pragma unroll
  for (int n = 0; n < 4; ++n)
#pragma unroll
    for (int reg = 0; reg < 4; ++reg) oacc[n][reg] *= f[reg];
#pragma unroll
  for (int ks = 0; ks < 2; ++ks) {
    const f16x8 pa = *(const f16x8*)(Plw + swzA(l16, ks * 32 + g * 8));
    f16x8 vb[4];
#pragma unroll
    for (int n = 0; n < 4; ++n) vb[n] = *(const f16x8*)(Vt + swzV(n * 16 + l16, ks * 32 + g * 8));
#pragma unroll
    for (int n = 0; n < 4; ++n)
      oacc[n] = __builtin_amdgcn_mfma_f32_16x16x32_f16(pa, vb[n], oacc[n], 0, 0, 0);
  }
}

__global__ __launch_bounds__(256) void attn_mfma(const _Float16* __restrict__ qkv,
                                                 _Float16* __restrict__ seq_out) {
  __shared__ __align__(16) _Float16 Kl[64 * 64];
  __shared__ __align__(16) _Float16 Vt[64 * 64];
  __shared__ __align__(16) _Float16 Pl[4][16 * 64];
  const int tid = threadIdx.x, lane = tid & 63, wq = tid >> 6;
  const int g = lane >> 4, l16 = lane & 15;
  const int p = blockIdx.x, hh = blockIdx.y, bb = blockIdx.z;
  const int qt0 = p, qt1 = 15 - p;
  const int ntt = qt1 + 1;

  f16x8 qf0[2], qf1[2];
  {
    const _Float16* q0 = qkv + (size_t)(bb * TT + qt0 * 64 + wq * 16 + l16) * QS + hh * 64;
    const _Float16* q1 = qkv + (size_t)(bb * TT + qt1 * 64 + wq * 16 + l16) * QS + hh * 64;
#pragma unroll
    for (int ks = 0; ks < 2; ++ks) {
      const f16x8 a0 = *(const f16x8*)(q0 + ks * 32 + g * 8);
      const f16x8 a1 = *(const f16x8*)(q1 + ks * 32 + g * 8);
#pragma unroll
      for (int j = 0; j < 8; ++j) {
        qf0[ks][j] = (_Float16)((float)a0[j] * 0.125f);
        qf1[ks][j] = (_Float16)((float)a1[j] * 0.125f);
      }
    }
  }

  f32x4 oacc0[4], oacc1[4];
#pragma unroll
  for (int n = 0; n < 4; ++n) {
    oacc0[n] = (f32x4){0.f, 0.f, 0.f, 0.f};
    oacc1[n] = (f32x4){0.f, 0.f, 0.f, 0.f};
  }
  float m0[4] = {-INFINITY, -INFINITY, -INFINITY, -INFINITY};
  float l0[4] = {0.f, 0.f, 0.f, 0.f};
  float m1[4] = {-INFINITY, -INFINITY, -INFINITY, -INFINITY};
  float l1[4] = {0.f, 0.f, 0.f, 0.f};

  const int skey = tid >> 2, sc4 = tid & 3;

  for (int tt = 0; tt < ntt; ++tt) {
    if (tt) __syncthreads();
    {
      const _Float16* kp = qkv + (size_t)(bb * TT + tt * 64 + skey) * QS + hh * 64 + 1024;
      const _Float16* vp = kp + 1024;
#pragma unroll
      for (int ii = 0; ii < 4; ++ii) {
        const int d0 = sc4 * 4 + ii * 16;
        *(f16x4*)(Kl + swzA(skey, d0)) = *(const f16x4*)(kp + d0);
        const f16x4 vv = *(const f16x4*)(vp + d0);
        Vt[swzV(d0 + 0, skey)] = vv[0];
        Vt[swzV(d0 + 1, skey)] = vv[1];
        Vt[swzV(d0 + 2, skey)] = vv[2];
        Vt[swzV(d0 + 3, skey)] = vv[3];
      }
    }
    __syncthreads();
    attn_step(qf1, oacc1, m1, l1, Kl, Vt, Pl[wq], tt == qt1, wq, g, l16);
    if (tt <= qt0)
      attn_step(qf0, oacc0, m0, l0, Kl, Vt, Pl[wq], tt == qt0, wq, g, l16);
  }
#pragma unroll
  for (int n = 0; n < 4; ++n) {
#pragma unroll
    for (int reg = 0; reg < 4; ++reg) {
      const int r0 = qt0 * 64 + wq * 16 + g * 4 + reg;
      const int r1 = qt1 * 64 + wq * 16 + g * 4 + reg;
      seq_out[(size_t)(bb * TT + r0) * DD + hh * 64 + n * 16 + l16] = (_Float16)(oacc0[n][reg] / l0[reg]);
      seq_out[(size_t)(bb * TT + r1) * DD + hh * 64 + n * 16 + l16] = (_Float16)(oacc1[n][reg] / l1[reg]);
    }
  }
}

// ============ fused Gram branch: exterior products + chunk-parallel scan + gated mean ============
// One wave per (b,h); lane L owns timesteps [16L,16L+16). Lane-private LDS segments (209 floats):
// [0..95] Jw, [96..191] rd, [192..207] gate. No __syncthreads needed (shfl-only cross-lane).
// Output: atomicAdd sigmoid(score*mscale)*gate/16 into gm[b*1024+t] (pre-zeroed in prep_all).
static __device__ __forceinline__ int midx(int i, int j) {
  return (i <= j) ? (i * (13 - i)) / 2 + (j - i) : (j * (13 - j)) / 2 + (i - j);
}
static __device__ __forceinline__ void ext6(const float* a, const float* b, float* L) {
  L[0] = a[0] * b[1] - a[1] * b[0];
  L[1] = a[0] * b[2] - a[2] * b[0];
  L[2] = a[0] * b[3] - a[3] * b[0];
  L[3] = a[1] * b[2] - a[2] * b[1];
  L[4] = a[1] * b[3] - a[3] * b[1];
  L[5] = a[2] * b[3] - a[3] * b[2];
  const float n = sqrtf(L[0]*L[0] + L[1]*L[1] + L[2]*L[2] + L[3]*L[3] + L[4]*L[4] + L[5]*L[5]);
  const float s = 1.f / fmaxf(n, 1e-12f);
#pragma unroll
  for (int i = 0; i < 6; ++i) L[i] *= s;
}

__global__ __launch_bounds__(64) void gram_scan(const _Float16* __restrict__ mega,
    const float* __restrict__ decay_logits, const float* __restrict__ iter_mix,
    const float* __restrict__ mem_scale, float* __restrict__ gm) {
  const int h = blockIdx.x & 15, b = blockIdx.x >> 4;
  const int lane = threadIdx.x;
  const float decay = 1.f / (1.f + __expf(-decay_logits[h]));
  const float alpha = 1.f / (1.f + __expf(-iter_mix[0]));
  const float msc = mem_scale[h];
  __shared__ float sd[64 * 209];
  float* seg = sd + lane * 209;
  const int tbase = lane * 16;

  // stage: compute exterior products for own 16 timesteps directly from mega's lines region
  for (int s = 0; s < 16; ++s) {
    const int t = tbase + s;
    const _Float16* row = mega + (size_t)(b * TT + t) * QS + 3072;
    float w1[4] = {0.f, 0.f, 0.f, 0.f}, w2[4], r1[4], r2[4];
    if (t > 0) {
#pragma unroll
      for (int i = 0; i < 4; ++i) w1[i] = (float)row[-QS + h * 4 + i];
    }
#pragma unroll
    for (int i = 0; i < 4; ++i) {
      w2[i] = (float)row[64 + h * 4 + i];
      r1[i] = (float)row[128 + h * 4 + i];
      r2[i] = (float)row[192 + h * 4 + i];
    }
    const float gp = (float)row[256 + h];
    float wl[6], rl[6];
    ext6(w1, w2, wl);
    ext6(r1, r2, rl);
    seg[s * 6 + 0] =  wl[5]; seg[s * 6 + 1] = -wl[4]; seg[s * 6 + 2] =  wl[3];
    seg[s * 6 + 3] =  wl[2]; seg[s * 6 + 4] = -wl[1]; seg[s * 6 + 5] =  wl[0];
#pragma unroll
    for (int i = 0; i < 6; ++i) seg[96 + s * 6 + i] = rl[i];
    seg[192 + s] = 1.f / (1.f + __expf(-gp));
  }

  // phase 1: end-anchored chunk summary C = sum_t d^(end-t) J_t J_t^T
  float C[21];
#pragma unroll
  for (int e = 0; e < 21; ++e) C[e] = 0.f;
  for (int s = 0; s < 16; ++s) {
    float J[6], dJ[6];
#pragma unroll
    for (int i = 0; i < 6; ++i) { J[i] = seg[s * 6 + i]; dJ[i] = decay * J[i]; }
#pragma unroll
    for (int i = 0; i < 6; ++i)
#pragma unroll
      for (int j = i; j < 6; ++j)
        C[midx(i, j)] = decay * C[midx(i, j)] + dJ[i] * J[j];
  }
  // phase 2: Hillis-Steele scan across lanes with factor d^(16*2^k), then shift
  const float d2 = decay * decay, d4 = d2 * d2, d8 = d4 * d4;
  float fk = d8 * d8;  // d^16
#pragma unroll
  for (int k = 0; k < 6; ++k) {
    const int off = 1 << k;
#pragma unroll
    for (int e = 0; e < 21; ++e) {
      const float u = __shfl(C[e], lane - off);
      if (lane >= off) C[e] += fk * u;
    }
    fk = fk * fk;
  }
  float M[21];
#pragma unroll
  for (int e = 0; e < 21; ++e) {
    const float u = __shfl(C[e], lane - 1);
    M[e] = (lane >= 1) ? u : 0.f;
  }
  // phase 3: re-run chunk computing scores; fold sigmoid+gate+mean into gm atomically
  float* gmp = gm + b * TT + tbase;
  for (int s = 0; s < 16; ++s) {
    float J[6], r[6];
#pragma unroll
    for (int i = 0; i < 6; ++i) { J[i] = seg[s * 6 + i]; r[i] = seg[96 + s * 6 + i]; }
    float rdM[6];
#pragma unroll
    for (int i = 0; i < 6; ++i) {
      float a = 0.f;
#pragma unroll
      for (int j = 0; j < 6; ++j) a += M[midx(i, j)] * r[j];
      rdM[i] = a;
    }
    float s1 = 0.f, s2 = 0.f;
#pragma unroll
    for (int i = 0; i < 6; ++i) { s1 += rdM[i] * r[i]; s2 += rdM[i] * rdM[i]; }
    const float score = (1.f - alpha) * s1 + alpha * s2;
    const float val = (1.f / (1.f + __expf(-score * msc))) * seg[192 + s];
    atomicAdd(&gmp[s], val * (1.f / 16.f));
    float dJ[6];
#pragma unroll
    for (int i = 0; i < 6; ++i) dJ[i] = decay * J[i];
#pragma unroll
    for (int i = 0; i < 6; ++i)
#pragma unroll
      for (int j = i; j < 6; ++j)
        M[midx(i, j)] = decay * M[midx(i, j)] + dJ[i] * J[j];
  }
}

// ============ combine: attnin = seq + gm*mv  (f16 out) ============
__global__ void combine_kernel(const _Float16* __restrict__ seq, const _Float16* __restrict__ mega,
    const float* __restrict__ gm, _Float16* __restrict__ outp) {
  const int i = blockIdx.x * 256 + threadIdx.x;  // f16x4 index, 524288 total
  const int bt = i >> 8, c4 = i & 255;
  const float g = gm[bt];
  const f16x4 s4 = *(const f16x4*)(seq + (size_t)i * 4);
  const f16x4 m4 = *(const f16x4*)(mega + (size_t)bt * QS + 3584 + c4 * 4);
  f16x4 o;
#pragma unroll
  for (int j = 0; j < 4; ++j) o[j] = (_Float16)((float)s4[j] + g * (float)m4[j]);
  *(f16x4*)(outp + (size_t)i * 4) = o;
}

// ============ dst = src + bias  (pre-init for atomic split-K GEMMs) ============
__global__ void addb_init(const float* __restrict__ src, const float* __restrict__ bias,
                          float* __restrict__ dst) {
  const size_t i = (size_t)blockIdx.x * 256 + threadIdx.x;
  const int c4 = (int)(i & 255);
  const float4 s = ((const float4*)src)[i];
  const float4 b = ((const float4*)bias)[c4];
  float4 o;
  o.x = s.x + b.x; o.y = s.y + b.y; o.z = s.z + b.z; o.w = s.w + b.w;
  ((float4*)dst)[i] = o;
}

extern "C" void kernel_launch(void* const* d_in, const int* in_sizes, int n_in,
                              void* d_out, int out_size, void* d_ws, size_t ws_size,
                              hipStream_t stream) {
  (void)in_sizes; (void)n_in; (void)out_size; (void)ws_size;
  const float* x       = (const float*)d_in[0];
  const float* ln1_g   = (const float*)d_in[1];
  const float* ln1_b   = (const float*)d_in[2];
  const float* Wqkv    = (const float*)d_in[3];
  const float* bqkv    = (const float*)d_in[4];
  const float* W1w     = (const float*)d_in[5];
  const float* W2w     = (const float*)d_in[6];
  const float* W1r     = (const float*)d_in[7];
  const float* W2r     = (const float*)d_in[8];
  const float* Wmv     = (const float*)d_in[9];
  const float* bmv     = (const float*)d_in[10];
  const float* Wmg     = (const float*)d_in[11];
  const float* bmg     = (const float*)d_in[12];
  const float* mscale  = (const float*)d_in[13];
  const float* itermix = (const float*)d_in[14];
  const float* dlogits = (const float*)d_in[15];
  const float* Wout    = (const float*)d_in[16];
  const float* bout    = (const float*)d_in[17];
  const float* ln2_g   = (const float*)d_in[18];
  const float* ln2_b   = (const float*)d_in[19];
  const float* Wfc     = (const float*)d_in[20];
  const float* bfc     = (const float*)d_in[21];
  const float* Wproj   = (const float*)d_in[22];
  const float* bproj   = (const float*)d_in[23];
  float* out = (float*)d_out;
  float* ws = (float*)d_ws;

  const size_t M1 = 1u << 20;
  _Float16* h16    = (_Float16*)ws;                         // 0 .. 1M1 (2M f16)
  _Float16* WmT    = (_Float16*)(ws + 1 * M1);              // 1M1 .. 3.25M1
  float*    bm     = ws + 3407872;                          // 3.25M1, 4608
  float*    gm     = ws + 3538944;                          // 2048
  float*    y      = ws + 4 * M1;                           // 4M1 .. 6M1
  _Float16* mega   = (_Float16*)(ws + 6 * M1);              // 6M1 .. 10.5M1 (2048x4608 f16)
  _Float16* fc16   = (_Float16*)(ws + 6 * M1);              // reuses mega (dead by then)
  _Float16* seq16  = (_Float16*)(ws + 11010048);            // 10.5M1 .. 11.5M1
  _Float16* WoutT  = (_Float16*)(ws + 12058624);            // 11.5M1 .. 12M1
  _Float16* WfcT   = (_Float16*)(ws + 12 * M1);             // 12M1 .. 14M1
  _Float16* WprojT = (_Float16*)(ws + 14 * M1);             // 14M1 .. 16M1

  // ---- fused weight prep + gm zero (1 dispatch) ----
  prep_all<<<3482, 256, 0, stream>>>(Wqkv, W1w, W2w, W1r, W2r, Wmg, Wmv, Wout, Wfc, Wproj,
                                     bqkv, bmg, bmv, WmT, WoutT, WfcT, WprojT, bm, gm);

  // ---- block ----
  ln16<<<2048, 256, 0, stream>>>(x, ln1_g, ln1_b, h16);
  gemm_t16<<<576, 512, 0, stream>>>(h16, WmT, bm, nullptr, mega, 4608, 1024, 0, 36, 1, 32);
  attn_mfma<<<dim3(8, 16, 2), 256, 0, stream>>>(mega, seq16);
  gram_scan<<<32, 64, 0, stream>>>(mega, dlogits, itermix, mscale, gm);
  combine_kernel<<<2048, 256, 0, stream>>>(seq16, mega, gm, h16);
  // y = attnin @ Wout + bout + x   (direct mode 3)
  gemm_t16<<<128, 512, 0, stream>>>(h16, WoutT, bout, x, y, 1024, 1024, 0, 8, 3, 32);
  ln16<<<2048, 256, 0, stream>>>(y, ln2_g, ln2_b, h16);
  // fc = gelu(h2 @ Wfc + bfc), stored f16 (overwrites mega)
  gemm_t16<<<512, 512, 0, stream>>>(h16, WfcT, bfc, nullptr, fc16, 4096, 1024, 1, 32, 1, 32);
  // out = y + bproj + fc @ Wproj   (split-K=4 atomics into pre-initialized out)
  addb_init<<<2048, 256, 0, stream>>>(y, bproj, out);
  gemm_t16<<<dim3(128, 4), 512, 0, stream>>>(fc16, WprojT, nullptr, nullptr, out, 1024, 4096, 0, 8, 2, 32);
}

// Round 15
// 245.365 us; speedup vs baseline: 1.0455x; 1.0455x over previous
//
#include <hip/hip_runtime.h>
#include <hip/hip_bf16.h>
#include <math.h>

typedef float f32x4 __attribute__((ext_vector_type(4)));
typedef _Float16 f16x8 __attribute__((ext_vector_type(8)));
typedef _Float16 f16x4 __attribute__((ext_vector_type(4)));

#define TT 1024
#define DD 1024
#define QS 4608   // mega row stride (f16): [qkv 3072 | lines 512 | mv 1024]

typedef __attribute__((address_space(1))) const void gas_void;
typedef __attribute__((address_space(3))) void las_void;
static __device__ __forceinline__ void gl_lds16(const void* g, void* l) {
  __builtin_amdgcn_global_load_lds((gas_void*)g, (las_void*)l, 16, 0, 0);
}

// ============ f16 GEMM (R13 proven): 128x128 tile, 512 thr (8 waves 4x2), BK=32, 3-slot vmcnt ring ============
// A[M][K] f16, Wt[N][K] f16 (pre-transposed). C = A·Wt^T (+bias)(+gelu).
// LDS linear [row][4 chunks of 8 f16]; content pre-swizzled: pos(row,q) holds chunk q^((row>>1)&3).
// Ring: stage(t+1) in flight across barrier (counted vmcnt(2)); stage(t+2) issued after barrier.
// mode: 1 = store f16 | 2 = atomicAdd f32 (pre-initialized buffer; bias ignored) | 3 = store f32 + bias + residual
__global__ __launch_bounds__(512) void gemm_t16(
    const _Float16* __restrict__ A, const _Float16* __restrict__ Wt,
    const float* __restrict__ bias, const float* __restrict__ residual,
    void* __restrict__ Cv, int N, int K, int act, int gx, int mode, int ktiles) {
  __shared__ __align__(16) _Float16 As[3][4096];   // 128x32 each
  __shared__ __align__(16) _Float16 Bs[3][4096];
  const int tid = threadIdx.x;
  const int lane = tid & 63;
  const int wid = tid >> 6;                 // 0..7
  const int wr = wid >> 1, wc = wid & 1;    // 4x2 wave grid; wave tile 32r x 64c
  const int g = lane >> 4, l16 = lane & 15;
  const int cpx = gridDim.x >> 3;
  const int wg = (blockIdx.x & 7) * cpx + (blockIdx.x >> 3);   // XCD swizzle
  const int row0 = (wg / gx) * 128, col0 = (wg % gx) * 128;
  const int kbeg = blockIdx.y * ktiles * 32;

  f32x4 acc[2][4];
#pragma unroll
  for (int m = 0; m < 2; ++m)
#pragma unroll
    for (int n = 0; n < 4; ++n) acc[m][n] = (f32x4){0.f, 0.f, 0.f, 0.f};

  const int srow = tid >> 2;
  const int goff = ((tid & 3) ^ ((srow >> 1) & 3)) << 3;
  const _Float16* agp = A + (size_t)(row0 + srow) * K + kbeg + goff;
  const _Float16* bgp = Wt + (size_t)(col0 + srow) * K + kbeg + goff;
  const int ldst = tid * 16;   // byte offset in tile

  const int prm = (l16 >> 1) & 3;  // fragment-read chunk perm

  // prologue: stage tiles 0 and 1 into slots 0 and 1
  gl_lds16(agp, (char*)As[0] + ldst);
  gl_lds16(bgp, (char*)Bs[0] + ldst);
  if (1 < ktiles) {
    gl_lds16(agp + 32, (char*)As[1] + ldst);
    gl_lds16(bgp + 32, (char*)Bs[1] + ldst);
  }

  int cs = 0, ss = 2;
  for (int kt = 0; kt < ktiles; ++kt) {
    if (kt < ktiles - 1) asm volatile("s_waitcnt vmcnt(2)" ::: "memory");
    else                 asm volatile("s_waitcnt vmcnt(0)" ::: "memory");
    __builtin_amdgcn_s_barrier();        // raw barrier: does NOT drain vmcnt
    __builtin_amdgcn_sched_barrier(0);   // no ds_read hoisted above the barrier
    if (kt + 2 < ktiles) {
      const int kp = (kt + 2) * 32;
      gl_lds16(agp + kp, (char*)As[ss] + ldst);
      gl_lds16(bgp + kp, (char*)Bs[ss] + ldst);
    }
    f16x8 af[2], bf[4];
#pragma unroll
    for (int m = 0; m < 2; ++m) {
      const int r = wr * 32 + m * 16 + l16;
      af[m] = *(const f16x8*)(As[cs] + r * 32 + ((g ^ prm) << 3));
    }
#pragma unroll
    for (int n = 0; n < 4; ++n) {
      const int c = wc * 64 + n * 16 + l16;
      bf[n] = *(const f16x8*)(Bs[cs] + c * 32 + ((g ^ prm) << 3));
    }
#pragma unroll
    for (int m = 0; m < 2; ++m)
#pragma unroll
      for (int n = 0; n < 4; ++n)
        acc[m][n] = __builtin_amdgcn_mfma_f32_16x16x32_f16(af[m], bf[n], acc[m][n], 0, 0, 0);
    cs = (cs == 2) ? 0 : cs + 1;
    ss = (ss == 2) ? 0 : ss + 1;
  }
#pragma unroll
  for (int m = 0; m < 2; ++m) {
#pragma unroll
    for (int n = 0; n < 4; ++n) {
      const int col = col0 + wc * 64 + n * 16 + l16;
      const float bv = (mode != 2 && bias) ? bias[col] : 0.f;
#pragma unroll
      for (int rg = 0; rg < 4; ++rg) {
        const int row = row0 + wr * 32 + m * 16 + g * 4 + rg;
        const size_t off = (size_t)row * N + col;
        float v = acc[m][n][rg] + bv;
        if (act == 1) v = 0.5f * v * (1.f + erff(v * 0.70710678118654752f));
        if (mode == 2) atomicAdd(&((float*)Cv)[off], v);
        else if (mode == 3) ((float*)Cv)[off] = v + residual[off];
        else ((_Float16*)Cv)[off] = (_Float16)v;
      }
    }
  }
}

// ============ fused weight prep: megaT + 3 transposes + biases + gm zero in ONE dispatch ============
static __device__ __forceinline__ void trans_tile(const float* __restrict__ W,
    _Float16* __restrict__ WT, int K, int N, int n0, int k0, int tid) {
  __shared__ float tile[64][65];
  const int tn = tid & 63, tk4 = tid >> 6;
#pragma unroll
  for (int it = 0; it < 16; ++it) {
    const int k = k0 + it * 4 + tk4;
    tile[tn][it * 4 + tk4] = W[(size_t)k * N + n0 + tn];
  }
  __syncthreads();
  const int on = tid >> 2, ok = tid & 3;
  f16x8 a, b;
#pragma unroll
  for (int j = 0; j < 8; ++j) {
    a[j] = (_Float16)tile[on][ok * 16 + j];
    b[j] = (_Float16)tile[on][ok * 16 + 8 + j];
  }
  _Float16* dst = WT + (size_t)(n0 + on) * K + k0 + ok * 16;
  *(f16x8*)dst = a;
  *(f16x8*)(dst + 8) = b;
}

__global__ __launch_bounds__(256) void prep_all(
    const float* __restrict__ Wqkv, const float* __restrict__ W1w, const float* __restrict__ W2w,
    const float* __restrict__ W1r, const float* __restrict__ W2r, const float* __restrict__ Wmg,
    const float* __restrict__ Wmv, const float* __restrict__ Wout, const float* __restrict__ Wfc,
    const float* __restrict__ Wproj, const float* __restrict__ bqkv, const float* __restrict__ bmg,
    const float* __restrict__ bmv, _Float16* __restrict__ WmT, _Float16* __restrict__ WoutT,
    _Float16* __restrict__ WfcT, _Float16* __restrict__ WprojT, float* __restrict__ bm,
    float* __restrict__ gm) {
  const int id = blockIdx.x;
  const int tid = threadIdx.x;
  if (id < 1152) {                      // megaT gather-transpose: 72 n-tiles x 16 k-tiles
    __shared__ float tile[64][65];
    const int n0 = (id % 72) * 64, k0 = (id / 72) * 64;
    const int tn = tid & 63, tk4 = tid >> 6;
#pragma unroll
    for (int it = 0; it < 16; ++it) {
      const int k = k0 + it * 4 + tk4;
      const int n = n0 + tn;
      float v;
      if (n < 3072) v = Wqkv[(size_t)k * 3072 + n];
      else if (n < 3136) v = W1w[k * 64 + n - 3072];
      else if (n < 3200) v = W2w[k * 64 + n - 3136];
      else if (n < 3264) v = W1r[k * 64 + n - 3200];
      else if (n < 3328) v = W2r[k * 64 + n - 3264];
      else if (n < 3344) v = Wmg[k * 16 + n - 3328];
      else if (n < 3584) v = 0.f;
      else v = Wmv[(size_t)k * 1024 + n - 3584];
      tile[tn][it * 4 + tk4] = v;
    }
    __syncthreads();
    const int on = tid >> 2, ok = tid & 3;
    f16x8 a, b;
#pragma unroll
    for (int j = 0; j < 8; ++j) {
      a[j] = (_Float16)tile[on][ok * 16 + j];
      b[j] = (_Float16)tile[on][ok * 16 + 8 + j];
    }
    _Float16* dst = WmT + (size_t)(n0 + on) * 1024 + k0 + ok * 16;
    *(f16x8*)dst = a;
    *(f16x8*)(dst + 8) = b;
  } else if (id < 1408) {               // WoutT: 16 x 16
    const int i2 = id - 1152;
    trans_tile(Wout, WoutT, 1024, 1024, (i2 % 16) * 64, (i2 / 16) * 64, tid);
  } else if (id < 2432) {               // WfcT: 64 x 16
    const int i2 = id - 1408;
    trans_tile(Wfc, WfcT, 1024, 4096, (i2 % 64) * 64, (i2 / 64) * 64, tid);
  } else if (id < 3456) {               // WprojT: 16 x 64
    const int i2 = id - 2432;
    trans_tile(Wproj, WprojT, 4096, 1024, (i2 % 16) * 64, (i2 / 16) * 64, tid);
  } else if (id < 3474) {               // bm: 18 blocks x 256
    const int col = (id - 3456) * 256 + tid;
    if (col < 4608) {
      float b = 0.f;
      if (col < 3072) b = bqkv[col];
      else if (col >= 3328 && col < 3344) b = bmg[col - 3328];
      else if (col >= 3584) b = bmv[col - 3584];
      bm[col] = b;
    }
  } else {                              // gm zero: 8 blocks x 256 = 2048
    gm[(id - 3474) * 256 + tid] = 0.f;
  }
}

// ============ LayerNorm -> f16 ============
__global__ __launch_bounds__(256) void ln16(const float* __restrict__ in,
    const float* __restrict__ gw, const float* __restrict__ bw, _Float16* __restrict__ out) {
  const int row = blockIdx.x, tid = threadIdx.x;
  const float* x = in + (size_t)row * DD;
  const float4 v = *(const float4*)(x + tid * 4);
  float s = v.x + v.y + v.z + v.w;
  float sq = v.x * v.x + v.y * v.y + v.z * v.z + v.w * v.w;
#pragma unroll
  for (int off = 32; off >= 1; off >>= 1) { s += __shfl_xor(s, off); sq += __shfl_xor(sq, off); }
  __shared__ float red[8];
  const int lane = tid & 63, wv = tid >> 6;
  if (lane == 0) { red[wv] = s; red[4 + wv] = sq; }
  __syncthreads();
  s = red[0] + red[1] + red[2] + red[3];
  sq = red[4] + red[5] + red[6] + red[7];
  const float mean = s * (1.f / 1024.f);
  const float var = sq * (1.f / 1024.f) - mean * mean;
  const float rstd = rsqrtf(var + 1e-5f);
  const float4 g4 = *(const float4*)(gw + tid * 4);
  const float4 b4 = *(const float4*)(bw + tid * 4);
  f16x4 o;
  o[0] = (_Float16)((v.x - mean) * rstd * g4.x + b4.x);
  o[1] = (_Float16)((v.y - mean) * rstd * g4.y + b4.y);
  o[2] = (_Float16)((v.z - mean) * rstd * g4.z + b4.z);
  o[3] = (_Float16)((v.w - mean) * rstd * g4.w + b4.w);
  *(f16x4*)(out + (size_t)row * DD + tid * 4) = o;
}

// ============ MFMA f16 causal flash attention, PAIRED q-tiles (qt=p and qt=15-p) ============
static __device__ __forceinline__ int swzA(int row, int k) {
  return row * 64 + ((((k >> 3) ^ row) & 7) << 3) + (k & 7);
}
static __device__ __forceinline__ int swzV(int row, int k) {
  return row * 64 + ((((k >> 3) ^ row ^ (row >> 3)) & 7) << 3) + (k & 7);
}

static __device__ __forceinline__ void attn_step(
    const f16x8* qf, f32x4* oacc, float* m, float* l,
    const _Float16* Kl, const _Float16* Vt, _Float16* Plw,
    bool diag, int wq, int g, int l16) {
  f32x4 s[4];
#pragma unroll
  for (int n = 0; n < 4; ++n) s[n] = (f32x4){0.f, 0.f, 0.f, 0.f};
#pragma unroll
  for (int ks = 0; ks < 2; ++ks) {
    f16x8 kf[4];
#pragma unroll
    for (int n = 0; n < 4; ++n) kf[n] = *(const f16x8*)(Kl + swzA(n * 16 + l16, ks * 32 + g * 8));
#pragma unroll
    for (int n = 0; n < 4; ++n)
      s[n] = __builtin_amdgcn_mfma_f32_16x16x32_f16(qf[ks], kf[n], s[n], 0, 0, 0);
  }
  if (diag) {
    const int rloc = wq * 16 + g * 4;
#pragma unroll
    for (int n = 0; n < 4; ++n) {
      const int cloc = n * 16 + l16;
#pragma unroll
      for (int reg = 0; reg < 4; ++reg)
        if (cloc > rloc + reg) s[n][reg] = -INFINITY;
    }
  }
  float f[4];
#pragma unroll
  for (int reg = 0; reg < 4; ++reg) {
    float t = fmaxf(fmaxf(s[0][reg], s[1][reg]), fmaxf(s[2][reg], s[3][reg]));
#pragma unroll
    for (int off = 1; off < 16; off <<= 1) t = fmaxf(t, __shfl_xor(t, off));
    const float nm = fmaxf(m[reg], t);
    f[reg] = __expf(m[reg] - nm);
    m[reg] = nm;
  }
  float rs[4] = {0.f, 0.f, 0.f, 0.f};
#pragma unroll
  for (int n = 0; n < 4; ++n) {
#pragma unroll
    for (int reg = 0; reg < 4; ++reg) {
      const float p = __expf(s[n][reg] - m[reg]);
      rs[reg] += p;
      Plw[swzA(g * 4 + reg, n * 16 + l16)] = (_Float16)p;
    }
  }
#pragma unroll
  for (int reg = 0; reg < 4; ++reg) {
    float t = rs[reg];
#pragma unroll
    for (int off = 1; off < 16; off <<= 1) t += __shfl_xor(t, off);
    l[reg] = l[reg] * f[reg] + t;
  }
#pragma unroll
  for (int n = 0; n < 4; ++n)
#pragma unroll
    for (int reg = 0; reg < 4; ++reg) oacc[n][reg] *= f[reg];
#pragma unroll
  for (int ks = 0; ks < 2; ++ks) {
    const f16x8 pa = *(const f16x8*)(Plw + swzA(l16, ks * 32 + g * 8));
    f16x8 vb[4];
#pragma unroll
    for (int n = 0; n < 4; ++n) vb[n] = *(const f16x8*)(Vt + swzV(n * 16 + l16, ks * 32 + g * 8));
#pragma unroll
    for (int n = 0; n < 4; ++n)
      oacc[n] = __builtin_amdgcn_mfma_f32_16x16x32_f16(pa, vb[n], oacc[n], 0, 0, 0);
  }
}

__global__ __launch_bounds__(256) void attn_mfma(const _Float16* __restrict__ qkv,
                                                 _Float16* __restrict__ seq_out) {
  __shared__ __align__(16) _Float16 Kl[64 * 64];
  __shared__ __align__(16) _Float16 Vt[64 * 64];
  __shared__ __align__(16) _Float16 Pl[4][16 * 64];
  const int tid = threadIdx.x, lane = tid & 63, wq = tid >> 6;
  const int g = lane >> 4, l16 = lane & 15;
  const int p = blockIdx.x, hh = blockIdx.y, bb = blockIdx.z;
  const int qt0 = p, qt1 = 15 - p;
  const int ntt = qt1 + 1;

  f16x8 qf0[2], qf1[2];
  {
    const _Float16* q0 = qkv + (size_t)(bb * TT + qt0 * 64 + wq * 16 + l16) * QS + hh * 64;
    const _Float16* q1 = qkv + (size_t)(bb * TT + qt1 * 64 + wq * 16 + l16) * QS + hh * 64;
#pragma unroll
    for (int ks = 0; ks < 2; ++ks) {
      const f16x8 a0 = *(const f16x8*)(q0 + ks * 32 + g * 8);
      const f16x8 a1 = *(const f16x8*)(q1 + ks * 32 + g * 8);
#pragma unroll
      for (int j = 0; j < 8; ++j) {
        qf0[ks][j] = (_Float16)((float)a0[j] * 0.125f);
        qf1[ks][j] = (_Float16)((float)a1[j] * 0.125f);
      }
    }
  }

  f32x4 oacc0[4], oacc1[4];
#pragma unroll
  for (int n = 0; n < 4; ++n) {
    oacc0[n] = (f32x4){0.f, 0.f, 0.f, 0.f};
    oacc1[n] = (f32x4){0.f, 0.f, 0.f, 0.f};
  }
  float m0[4] = {-INFINITY, -INFINITY, -INFINITY, -INFINITY};
  float l0[4] = {0.f, 0.f, 0.f, 0.f};
  float m1[4] = {-INFINITY, -INFINITY, -INFINITY, -INFINITY};
  float l1[4] = {0.f, 0.f, 0.f, 0.f};

  const int skey = tid >> 2, sc4 = tid & 3;

  for (int tt = 0; tt < ntt; ++tt) {
    if (tt) __syncthreads();
    {
      const _Float16* kp = qkv + (size_t)(bb * TT + tt * 64 + skey) * QS + hh * 64 + 1024;
      const _Float16* vp = kp + 1024;
#pragma unroll
      for (int ii = 0; ii < 4; ++ii) {
        const int d0 = sc4 * 4 + ii * 16;
        *(f16x4*)(Kl + swzA(skey, d0)) = *(const f16x4*)(kp + d0);
        const f16x4 vv = *(const f16x4*)(vp + d0);
        Vt[swzV(d0 + 0, skey)] = vv[0];
        Vt[swzV(d0 + 1, skey)] = vv[1];
        Vt[swzV(d0 + 2, skey)] = vv[2];
        Vt[swzV(d0 + 3, skey)] = vv[3];
      }
    }
    __syncthreads();
    attn_step(qf1, oacc1, m1, l1, Kl, Vt, Pl[wq], tt == qt1, wq, g, l16);
    if (tt <= qt0)
      attn_step(qf0, oacc0, m0, l0, Kl, Vt, Pl[wq], tt == qt0, wq, g, l16);
  }
#pragma unroll
  for (int n = 0; n < 4; ++n) {
#pragma unroll
    for (int reg = 0; reg < 4; ++reg) {
      const int r0 = qt0 * 64 + wq * 16 + g * 4 + reg;
      const int r1 = qt1 * 64 + wq * 16 + g * 4 + reg;
      seq_out[(size_t)(bb * TT + r0) * DD + hh * 64 + n * 16 + l16] = (_Float16)(oacc0[n][reg] / l0[reg]);
      seq_out[(size_t)(bb * TT + r1) * DD + hh * 64 + n * 16 + l16] = (_Float16)(oacc1[n][reg] / l1[reg]);
    }
  }
}

// ============ fused Gram branch: exterior products + chunk-parallel scan + gated mean ============
static __device__ __forceinline__ int midx(int i, int j) {
  return (i <= j) ? (i * (13 - i)) / 2 + (j - i) : (j * (13 - j)) / 2 + (i - j);
}
static __device__ __forceinline__ void ext6(const float* a, const float* b, float* L) {
  L[0] = a[0] * b[1] - a[1] * b[0];
  L[1] = a[0] * b[2] - a[2] * b[0];
  L[2] = a[0] * b[3] - a[3] * b[0];
  L[3] = a[1] * b[2] - a[2] * b[1];
  L[4] = a[1] * b[3] - a[3] * b[1];
  L[5] = a[2] * b[3] - a[3] * b[2];
  const float n = sqrtf(L[0]*L[0] + L[1]*L[1] + L[2]*L[2] + L[3]*L[3] + L[4]*L[4] + L[5]*L[5]);
  const float s = 1.f / fmaxf(n, 1e-12f);
#pragma unroll
  for (int i = 0; i < 6; ++i) L[i] *= s;
}

__global__ __launch_bounds__(64) void gram_scan(const _Float16* __restrict__ mega,
    const float* __restrict__ decay_logits, const float* __restrict__ iter_mix,
    const float* __restrict__ mem_scale, float* __restrict__ gm) {
  const int h = blockIdx.x & 15, b = blockIdx.x >> 4;
  const int lane = threadIdx.x;
  const float decay = 1.f / (1.f + __expf(-decay_logits[h]));
  const float alpha = 1.f / (1.f + __expf(-iter_mix[0]));
  const float msc = mem_scale[h];
  __shared__ float sd[64 * 209];
  float* seg = sd + lane * 209;
  const int tbase = lane * 16;

  for (int s = 0; s < 16; ++s) {
    const int t = tbase + s;
    const _Float16* row = mega + (size_t)(b * TT + t) * QS + 3072;
    float w1[4] = {0.f, 0.f, 0.f, 0.f}, w2[4], r1[4], r2[4];
    if (t > 0) {
#pragma unroll
      for (int i = 0; i < 4; ++i) w1[i] = (float)row[-QS + h * 4 + i];
    }
#pragma unroll
    for (int i = 0; i < 4; ++i) {
      w2[i] = (float)row[64 + h * 4 + i];
      r1[i] = (float)row[128 + h * 4 + i];
      r2[i] = (float)row[192 + h * 4 + i];
    }
    const float gp = (float)row[256 + h];
    float wl[6], rl[6];
    ext6(w1, w2, wl);
    ext6(r1, r2, rl);
    seg[s * 6 + 0] =  wl[5]; seg[s * 6 + 1] = -wl[4]; seg[s * 6 + 2] =  wl[3];
    seg[s * 6 + 3] =  wl[2]; seg[s * 6 + 4] = -wl[1]; seg[s * 6 + 5] =  wl[0];
#pragma unroll
    for (int i = 0; i < 6; ++i) seg[96 + s * 6 + i] = rl[i];
    seg[192 + s] = 1.f / (1.f + __expf(-gp));
  }

  float C[21];
#pragma unroll
  for (int e = 0; e < 21; ++e) C[e] = 0.f;
  for (int s = 0; s < 16; ++s) {
    float J[6], dJ[6];
#pragma unroll
    for (int i = 0; i < 6; ++i) { J[i] = seg[s * 6 + i]; dJ[i] = decay * J[i]; }
#pragma unroll
    for (int i = 0; i < 6; ++i)
#pragma unroll
      for (int j = i; j < 6; ++j)
        C[midx(i, j)] = decay * C[midx(i, j)] + dJ[i] * J[j];
  }
  const float d2 = decay * decay, d4 = d2 * d2, d8 = d4 * d4;
  float fk = d8 * d8;  // d^16
#pragma unroll
  for (int k = 0; k < 6; ++k) {
    const int off = 1 << k;
#pragma unroll
    for (int e = 0; e < 21; ++e) {
      const float u = __shfl(C[e], lane - off);
      if (lane >= off) C[e] += fk * u;
    }
    fk = fk * fk;
  }
  float M[21];
#pragma unroll
  for (int e = 0; e < 21; ++e) {
    const float u = __shfl(C[e], lane - 1);
    M[e] = (lane >= 1) ? u : 0.f;
  }
  float* gmp = gm + b * TT + tbase;
  for (int s = 0; s < 16; ++s) {
    float J[6], r[6];
#pragma unroll
    for (int i = 0; i < 6; ++i) { J[i] = seg[s * 6 + i]; r[i] = seg[96 + s * 6 + i]; }
    float rdM[6];
#pragma unroll
    for (int i = 0; i < 6; ++i) {
      float a = 0.f;
#pragma unroll
      for (int j = 0; j < 6; ++j) a += M[midx(i, j)] * r[j];
      rdM[i] = a;
    }
    float s1 = 0.f, s2 = 0.f;
#pragma unroll
    for (int i = 0; i < 6; ++i) { s1 += rdM[i] * r[i]; s2 += rdM[i] * rdM[i]; }
    const float score = (1.f - alpha) * s1 + alpha * s2;
    const float val = (1.f / (1.f + __expf(-score * msc))) * seg[192 + s];
    atomicAdd(&gmp[s], val * (1.f / 16.f));
    float dJ[6];
#pragma unroll
    for (int i = 0; i < 6; ++i) dJ[i] = decay * J[i];
#pragma unroll
    for (int i = 0; i < 6; ++i)
#pragma unroll
      for (int j = i; j < 6; ++j)
        M[midx(i, j)] = decay * M[midx(i, j)] + dJ[i] * J[j];
  }
}

// ============ combine: attnin = seq + gm*mv  (f16 out) ============
__global__ void combine_kernel(const _Float16* __restrict__ seq, const _Float16* __restrict__ mega,
    const float* __restrict__ gm, _Float16* __restrict__ outp) {
  const int i = blockIdx.x * 256 + threadIdx.x;  // f16x4 index, 524288 total
  const int bt = i >> 8, c4 = i & 255;
  const float g = gm[bt];
  const f16x4 s4 = *(const f16x4*)(seq + (size_t)i * 4);
  const f16x4 m4 = *(const f16x4*)(mega + (size_t)bt * QS + 3584 + c4 * 4);
  f16x4 o;
#pragma unroll
  for (int j = 0; j < 4; ++j) o[j] = (_Float16)((float)s4[j] + g * (float)m4[j]);
  *(f16x4*)(outp + (size_t)i * 4) = o;
}

// ============ dst = src + bias  (pre-init for atomic split-K GEMMs) ============
__global__ void addb_init(const float* __restrict__ src, const float* __restrict__ bias,
                          float* __restrict__ dst) {
  const size_t i = (size_t)blockIdx.x * 256 + threadIdx.x;
  const int c4 = (int)(i & 255);
  const float4 s = ((const float4*)src)[i];
  const float4 b = ((const float4*)bias)[c4];
  float4 o;
  o.x = s.x + b.x; o.y = s.y + b.y; o.z = s.z + b.z; o.w = s.w + b.w;
  ((float4*)dst)[i] = o;
}

extern "C" void kernel_launch(void* const* d_in, const int* in_sizes, int n_in,
                              void* d_out, int out_size, void* d_ws, size_t ws_size,
                              hipStream_t stream) {
  (void)in_sizes; (void)n_in; (void)out_size; (void)ws_size;
  const float* x       = (const float*)d_in[0];
  const float* ln1_g   = (const float*)d_in[1];
  const float* ln1_b   = (const float*)d_in[2];
  const float* Wqkv    = (const float*)d_in[3];
  const float* bqkv    = (const float*)d_in[4];
  const float* W1w     = (const float*)d_in[5];
  const float* W2w     = (const float*)d_in[6];
  const float* W1r     = (const float*)d_in[7];
  const float* W2r     = (const float*)d_in[8];
  const float* Wmv     = (const float*)d_in[9];
  const float* bmv     = (const float*)d_in[10];
  const float* Wmg     = (const float*)d_in[11];
  const float* bmg     = (const float*)d_in[12];
  const float* mscale  = (const float*)d_in[13];
  const float* itermix = (const float*)d_in[14];
  const float* dlogits = (const float*)d_in[15];
  const float* Wout    = (const float*)d_in[16];
  const float* bout    = (const float*)d_in[17];
  const float* ln2_g   = (const float*)d_in[18];
  const float* ln2_b   = (const float*)d_in[19];
  const float* Wfc     = (const float*)d_in[20];
  const float* bfc     = (const float*)d_in[21];
  const float* Wproj   = (const float*)d_in[22];
  const float* bproj   = (const float*)d_in[23];
  float* out = (float*)d_out;
  float* ws = (float*)d_ws;

  const size_t M1 = 1u << 20;
  _Float16* h16    = (_Float16*)ws;                         // 0 .. 1M1 (2M f16)
  _Float16* WmT    = (_Float16*)(ws + 1 * M1);              // 1M1 .. 3.25M1
  float*    bm     = ws + 3407872;                          // 3.25M1, 4608
  float*    gm     = ws + 3538944;                          // 2048
  float*    y      = ws + 4 * M1;                           // 4M1 .. 6M1
  _Float16* mega   = (_Float16*)(ws + 6 * M1);              // 6M1 .. 10.5M1 (2048x4608 f16)
  _Float16* fc16   = (_Float16*)(ws + 6 * M1);              // reuses mega (dead by then)
  _Float16* seq16  = (_Float16*)(ws + 11010048);            // 10.5M1 .. 11.5M1
  _Float16* WoutT  = (_Float16*)(ws + 12058624);            // 11.5M1 .. 12M1
  _Float16* WfcT   = (_Float16*)(ws + 12 * M1);             // 12M1 .. 14M1
  _Float16* WprojT = (_Float16*)(ws + 14 * M1);             // 14M1 .. 16M1

  // ---- fused weight prep + gm zero (1 dispatch) ----
  prep_all<<<3482, 256, 0, stream>>>(Wqkv, W1w, W2w, W1r, W2r, Wmg, Wmv, Wout, Wfc, Wproj,
                                     bqkv, bmg, bmv, WmT, WoutT, WfcT, WprojT, bm, gm);

  // ---- block ----
  ln16<<<2048, 256, 0, stream>>>(x, ln1_g, ln1_b, h16);
  gemm_t16<<<576, 512, 0, stream>>>(h16, WmT, bm, nullptr, mega, 4608, 1024, 0, 36, 1, 32);
  attn_mfma<<<dim3(8, 16, 2), 256, 0, stream>>>(mega, seq16);
  gram_scan<<<32, 64, 0, stream>>>(mega, dlogits, itermix, mscale, gm);
  combine_kernel<<<2048, 256, 0, stream>>>(seq16, mega, gm, h16);
  // y = attnin @ Wout + bout + x   (direct mode 3)
  gemm_t16<<<128, 512, 0, stream>>>(h16, WoutT, bout, x, y, 1024, 1024, 0, 8, 3, 32);
  ln16<<<2048, 256, 0, stream>>>(y, ln2_g, ln2_b, h16);
  // fc = gelu(h2 @ Wfc + bfc), stored f16 (overwrites mega)
  gemm_t16<<<512, 512, 0, stream>>>(h16, WfcT, bfc, nullptr, fc16, 4096, 1024, 1, 32, 1, 32);
  // out = y + bproj + fc @ Wproj   (split-K=4 atomics into pre-initialized out)
  addb_init<<<2048, 256, 0, stream>>>(y, bproj, out);
  gemm_t16<<<dim3(128, 4), 512, 0, stream>>>(fc16, WprojT, nullptr, nullptr, out, 1024, 4096, 0, 8, 2, 32);
}

// Round 16
// 235.853 us; speedup vs baseline: 1.0877x; 1.0403x over previous
//
#include <hip/hip_runtime.h>
#include <hip/hip_bf16.h>
#include <math.h>

typedef float f32x4 __attribute__((ext_vector_type(4)));
typedef _Float16 f16x8 __attribute__((ext_vector_type(8)));
typedef _Float16 f16x4 __attribute__((ext_vector_type(4)));

#define TT 1024
#define DD 1024
#define QS 4608   // mega row stride (f16): [qkv 3072 | lines 512 | mv 1024]

typedef __attribute__((address_space(1))) const void gas_void;
typedef __attribute__((address_space(3))) void las_void;
static __device__ __forceinline__ void gl_lds16(const void* g, void* l) {
  __builtin_amdgcn_global_load_lds((gas_void*)g, (las_void*)l, 16, 0, 0);
}

// ============ f16 GEMM (R13 proven): 128x128 tile, 512 thr (8 waves 4x2), BK=32, 3-slot vmcnt ring ============
// A[M][K] f16, Wt[N][K] f16 (pre-transposed). C = A·Wt^T (+bias)(+gelu).
// LDS linear [row][4 chunks of 8 f16]; content pre-swizzled: pos(row,q) holds chunk q^((row>>1)&3).
// Ring: stage(t+1) in flight across barrier (counted vmcnt(2)); stage(t+2) issued after barrier.
// mode: 1 = store f16 | 2 = atomicAdd f32 (pre-initialized buffer; bias ignored) | 3 = store f32 + bias + residual
__global__ __launch_bounds__(512) void gemm_t16(
    const _Float16* __restrict__ A, const _Float16* __restrict__ Wt,
    const float* __restrict__ bias, const float* __restrict__ residual,
    void* __restrict__ Cv, int N, int K, int act, int gx, int mode, int ktiles) {
  __shared__ __align__(16) _Float16 As[3][4096];   // 128x32 each
  __shared__ __align__(16) _Float16 Bs[3][4096];
  const int tid = threadIdx.x;
  const int lane = tid & 63;
  const int wid = tid >> 6;                 // 0..7
  const int wr = wid >> 1, wc = wid & 1;    // 4x2 wave grid; wave tile 32r x 64c
  const int g = lane >> 4, l16 = lane & 15;
  const int cpx = gridDim.x >> 3;
  const int wg = (blockIdx.x & 7) * cpx + (blockIdx.x >> 3);   // XCD swizzle
  const int row0 = (wg / gx) * 128, col0 = (wg % gx) * 128;
  const int kbeg = blockIdx.y * ktiles * 32;

  f32x4 acc[2][4];
#pragma unroll
  for (int m = 0; m < 2; ++m)
#pragma unroll
    for (int n = 0; n < 4; ++n) acc[m][n] = (f32x4){0.f, 0.f, 0.f, 0.f};

  const int srow = tid >> 2;
  const int goff = ((tid & 3) ^ ((srow >> 1) & 3)) << 3;
  const _Float16* agp = A + (size_t)(row0 + srow) * K + kbeg + goff;
  const _Float16* bgp = Wt + (size_t)(col0 + srow) * K + kbeg + goff;
  const int ldst = tid * 16;   // byte offset in tile

  const int prm = (l16 >> 1) & 3;  // fragment-read chunk perm

  // prologue: stage tiles 0 and 1 into slots 0 and 1
  gl_lds16(agp, (char*)As[0] + ldst);
  gl_lds16(bgp, (char*)Bs[0] + ldst);
  if (1 < ktiles) {
    gl_lds16(agp + 32, (char*)As[1] + ldst);
    gl_lds16(bgp + 32, (char*)Bs[1] + ldst);
  }

  int cs = 0, ss = 2;
  for (int kt = 0; kt < ktiles; ++kt) {
    if (kt < ktiles - 1) asm volatile("s_waitcnt vmcnt(2)" ::: "memory");
    else                 asm volatile("s_waitcnt vmcnt(0)" ::: "memory");
    __builtin_amdgcn_s_barrier();        // raw barrier: does NOT drain vmcnt
    __builtin_amdgcn_sched_barrier(0);   // no ds_read hoisted above the barrier
    if (kt + 2 < ktiles) {
      const int kp = (kt + 2) * 32;
      gl_lds16(agp + kp, (char*)As[ss] + ldst);
      gl_lds16(bgp + kp, (char*)Bs[ss] + ldst);
    }
    f16x8 af[2], bf[4];
#pragma unroll
    for (int m = 0; m < 2; ++m) {
      const int r = wr * 32 + m * 16 + l16;
      af[m] = *(const f16x8*)(As[cs] + r * 32 + ((g ^ prm) << 3));
    }
#pragma unroll
    for (int n = 0; n < 4; ++n) {
      const int c = wc * 64 + n * 16 + l16;
      bf[n] = *(const f16x8*)(Bs[cs] + c * 32 + ((g ^ prm) << 3));
    }
#pragma unroll
    for (int m = 0; m < 2; ++m)
#pragma unroll
      for (int n = 0; n < 4; ++n)
        acc[m][n] = __builtin_amdgcn_mfma_f32_16x16x32_f16(af[m], bf[n], acc[m][n], 0, 0, 0);
    cs = (cs == 2) ? 0 : cs + 1;
    ss = (ss == 2) ? 0 : ss + 1;
  }
#pragma unroll
  for (int m = 0; m < 2; ++m) {
#pragma unroll
    for (int n = 0; n < 4; ++n) {
      const int col = col0 + wc * 64 + n * 16 + l16;
      const float bv = (mode != 2 && bias) ? bias[col] : 0.f;
#pragma unroll
      for (int rg = 0; rg < 4; ++rg) {
        const int row = row0 + wr * 32 + m * 16 + g * 4 + rg;
        const size_t off = (size_t)row * N + col;
        float v = acc[m][n][rg] + bv;
        if (act == 1) v = 0.5f * v * (1.f + erff(v * 0.70710678118654752f));
        if (mode == 2) atomicAdd(&((float*)Cv)[off], v);
        else if (mode == 3) ((float*)Cv)[off] = v + residual[off];
        else ((_Float16*)Cv)[off] = (_Float16)v;
      }
    }
  }
}

// ============ fused weight prep: megaT + 3 transposes + biases in ONE dispatch ============
static __device__ __forceinline__ void trans_tile(const float* __restrict__ W,
    _Float16* __restrict__ WT, int K, int N, int n0, int k0, int tid) {
  __shared__ float tile[64][65];
  const int tn = tid & 63, tk4 = tid >> 6;
#pragma unroll
  for (int it = 0; it < 16; ++it) {
    const int k = k0 + it * 4 + tk4;
    tile[tn][it * 4 + tk4] = W[(size_t)k * N + n0 + tn];
  }
  __syncthreads();
  const int on = tid >> 2, ok = tid & 3;
  f16x8 a, b;
#pragma unroll
  for (int j = 0; j < 8; ++j) {
    a[j] = (_Float16)tile[on][ok * 16 + j];
    b[j] = (_Float16)tile[on][ok * 16 + 8 + j];
  }
  _Float16* dst = WT + (size_t)(n0 + on) * K + k0 + ok * 16;
  *(f16x8*)dst = a;
  *(f16x8*)(dst + 8) = b;
}

__global__ __launch_bounds__(256) void prep_all(
    const float* __restrict__ Wqkv, const float* __restrict__ W1w, const float* __restrict__ W2w,
    const float* __restrict__ W1r, const float* __restrict__ W2r, const float* __restrict__ Wmg,
    const float* __restrict__ Wmv, const float* __restrict__ Wout, const float* __restrict__ Wfc,
    const float* __restrict__ Wproj, const float* __restrict__ bqkv, const float* __restrict__ bmg,
    const float* __restrict__ bmv, _Float16* __restrict__ WmT, _Float16* __restrict__ WoutT,
    _Float16* __restrict__ WfcT, _Float16* __restrict__ WprojT, float* __restrict__ bm) {
  const int id = blockIdx.x;
  const int tid = threadIdx.x;
  if (id < 1152) {                      // megaT gather-transpose: 72 n-tiles x 16 k-tiles
    __shared__ float tile[64][65];
    const int n0 = (id % 72) * 64, k0 = (id / 72) * 64;
    const int tn = tid & 63, tk4 = tid >> 6;
#pragma unroll
    for (int it = 0; it < 16; ++it) {
      const int k = k0 + it * 4 + tk4;
      const int n = n0 + tn;
      float v;
      if (n < 3072) v = Wqkv[(size_t)k * 3072 + n];
      else if (n < 3136) v = W1w[k * 64 + n - 3072];
      else if (n < 3200) v = W2w[k * 64 + n - 3136];
      else if (n < 3264) v = W1r[k * 64 + n - 3200];
      else if (n < 3328) v = W2r[k * 64 + n - 3264];
      else if (n < 3344) v = Wmg[k * 16 + n - 3328];
      else if (n < 3584) v = 0.f;
      else v = Wmv[(size_t)k * 1024 + n - 3584];
      tile[tn][it * 4 + tk4] = v;
    }
    __syncthreads();
    const int on = tid >> 2, ok = tid & 3;
    f16x8 a, b;
#pragma unroll
    for (int j = 0; j < 8; ++j) {
      a[j] = (_Float16)tile[on][ok * 16 + j];
      b[j] = (_Float16)tile[on][ok * 16 + 8 + j];
    }
    _Float16* dst = WmT + (size_t)(n0 + on) * 1024 + k0 + ok * 16;
    *(f16x8*)dst = a;
    *(f16x8*)(dst + 8) = b;
  } else if (id < 1408) {               // WoutT: 16 x 16
    const int i2 = id - 1152;
    trans_tile(Wout, WoutT, 1024, 1024, (i2 % 16) * 64, (i2 / 16) * 64, tid);
  } else if (id < 2432) {               // WfcT: 64 x 16
    const int i2 = id - 1408;
    trans_tile(Wfc, WfcT, 1024, 4096, (i2 % 64) * 64, (i2 / 64) * 64, tid);
  } else if (id < 3456) {               // WprojT: 16 x 64
    const int i2 = id - 2432;
    trans_tile(Wproj, WprojT, 4096, 1024, (i2 % 16) * 64, (i2 / 16) * 64, tid);
  } else {                              // bm: 18 blocks x 256
    const int col = (id - 3456) * 256 + tid;
    if (col < 4608) {
      float b = 0.f;
      if (col < 3072) b = bqkv[col];
      else if (col >= 3328 && col < 3344) b = bmg[col - 3328];
      else if (col >= 3584) b = bmv[col - 3584];
      bm[col] = b;
    }
  }
}

// ============ LayerNorm -> f16 ============
__global__ __launch_bounds__(256) void ln16(const float* __restrict__ in,
    const float* __restrict__ gw, const float* __restrict__ bw, _Float16* __restrict__ out) {
  const int row = blockIdx.x, tid = threadIdx.x;
  const float* x = in + (size_t)row * DD;
  const float4 v = *(const float4*)(x + tid * 4);
  float s = v.x + v.y + v.z + v.w;
  float sq = v.x * v.x + v.y * v.y + v.z * v.z + v.w * v.w;
#pragma unroll
  for (int off = 32; off >= 1; off >>= 1) { s += __shfl_xor(s, off); sq += __shfl_xor(sq, off); }
  __shared__ float red[8];
  const int lane = tid & 63, wv = tid >> 6;
  if (lane == 0) { red[wv] = s; red[4 + wv] = sq; }
  __syncthreads();
  s = red[0] + red[1] + red[2] + red[3];
  sq = red[4] + red[5] + red[6] + red[7];
  const float mean = s * (1.f / 1024.f);
  const float var = sq * (1.f / 1024.f) - mean * mean;
  const float rstd = rsqrtf(var + 1e-5f);
  const float4 g4 = *(const float4*)(gw + tid * 4);
  const float4 b4 = *(const float4*)(bw + tid * 4);
  f16x4 o;
  o[0] = (_Float16)((v.x - mean) * rstd * g4.x + b4.x);
  o[1] = (_Float16)((v.y - mean) * rstd * g4.y + b4.y);
  o[2] = (_Float16)((v.z - mean) * rstd * g4.z + b4.z);
  o[3] = (_Float16)((v.w - mean) * rstd * g4.w + b4.w);
  *(f16x4*)(out + (size_t)row * DD + tid * 4) = o;
}

// ============ MFMA f16 causal flash attention, PAIRED q-tiles (qt=p and qt=15-p) ============
static __device__ __forceinline__ int swzA(int row, int k) {
  return row * 64 + ((((k >> 3) ^ row) & 7) << 3) + (k & 7);
}
static __device__ __forceinline__ int swzV(int row, int k) {
  return row * 64 + ((((k >> 3) ^ row ^ (row >> 3)) & 7) << 3) + (k & 7);
}

static __device__ __forceinline__ void attn_step(
    const f16x8* qf, f32x4* oacc, float* m, float* l,
    const _Float16* Kl, const _Float16* Vt, _Float16* Plw,
    bool diag, int wq, int g, int l16) {
  f32x4 s[4];
#pragma unroll
  for (int n = 0; n < 4; ++n) s[n] = (f32x4){0.f, 0.f, 0.f, 0.f};
#pragma unroll
  for (int ks = 0; ks < 2; ++ks) {
    f16x8 kf[4];
#pragma unroll
    for (int n = 0; n < 4; ++n) kf[n] = *(const f16x8*)(Kl + swzA(n * 16 + l16, ks * 32 + g * 8));
#pragma unroll
    for (int n = 0; n < 4; ++n)
      s[n] = __builtin_amdgcn_mfma_f32_16x16x32_f16(qf[ks], kf[n], s[n], 0, 0, 0);
  }
  if (diag) {
    const int rloc = wq * 16 + g * 4;
#pragma unroll
    for (int n = 0; n < 4; ++n) {
      const int cloc = n * 16 + l16;
#pragma unroll
      for (int reg = 0; reg < 4; ++reg)
        if (cloc > rloc + reg) s[n][reg] = -INFINITY;
    }
  }
  float f[4];
#pragma unroll
  for (int reg = 0; reg < 4; ++reg) {
    float t = fmaxf(fmaxf(s[0][reg], s[1][reg]), fmaxf(s[2][reg], s[3][reg]));
#pragma unroll
    for (int off = 1; off < 16; off <<= 1) t = fmaxf(t, __shfl_xor(t, off));
    const float nm = fmaxf(m[reg], t);
    f[reg] = __expf(m[reg] - nm);
    m[reg] = nm;
  }
  float rs[4] = {0.f, 0.f, 0.f, 0.f};
#pragma unroll
  for (int n = 0; n < 4; ++n) {
#pragma unroll
    for (int reg = 0; reg < 4; ++reg) {
      const float p = __expf(s[n][reg] - m[reg]);
      rs[reg] += p;
      Plw[swzA(g * 4 + reg, n * 16 + l16)] = (_Float16)p;
    }
  }
#pragma unroll
  for (int reg = 0; reg < 4; ++reg) {
    float t = rs[reg];
#pragma unroll
    for (int off = 1; off < 16; off <<= 1) t += __shfl_xor(t, off);
    l[reg] = l[reg] * f[reg] + t;
  }
#pragma unroll
  for (int n = 0; n < 4; ++n)
#pragma unroll
    for (int reg = 0; reg < 4; ++reg) oacc[n][reg] *= f[reg];
#pragma unroll
  for (int ks = 0; ks < 2; ++ks) {
    const f16x8 pa = *(const f16x8*)(Plw + swzA(l16, ks * 32 + g * 8));
    f16x8 vb[4];
#pragma unroll
    for (int n = 0; n < 4; ++n) vb[n] = *(const f16x8*)(Vt + swzV(n * 16 + l16, ks * 32 + g * 8));
#pragma unroll
    for (int n = 0; n < 4; ++n)
      oacc[n] = __builtin_amdgcn_mfma_f32_16x16x32_f16(pa, vb[n], oacc[n], 0, 0, 0);
  }
}

__global__ __launch_bounds__(256) void attn_mfma(const _Float16* __restrict__ qkv,
                                                 _Float16* __restrict__ seq_out) {
  __shared__ __align__(16) _Float16 Kl[64 * 64];
  __shared__ __align__(16) _Float16 Vt[64 * 64];
  __shared__ __align__(16) _Float16 Pl[4][16 * 64];
  const int tid = threadIdx.x, lane = tid & 63, wq = tid >> 6;
  const int g = lane >> 4, l16 = lane & 15;
  const int p = blockIdx.x, hh = blockIdx.y, bb = blockIdx.z;
  const int qt0 = p, qt1 = 15 - p;
  const int ntt = qt1 + 1;

  f16x8 qf0[2], qf1[2];
  {
    const _Float16* q0 = qkv + (size_t)(bb * TT + qt0 * 64 + wq * 16 + l16) * QS + hh * 64;
    const _Float16* q1 = qkv + (size_t)(bb * TT + qt1 * 64 + wq * 16 + l16) * QS + hh * 64;
#pragma unroll
    for (int ks = 0; ks < 2; ++ks) {
      const f16x8 a0 = *(const f16x8*)(q0 + ks * 32 + g * 8);
      const f16x8 a1 = *(const f16x8*)(q1 + ks * 32 + g * 8);
#pragma unroll
      for (int j = 0; j < 8; ++j) {
        qf0[ks][j] = (_Float16)((float)a0[j] * 0.125f);
        qf1[ks][j] = (_Float16)((float)a1[j] * 0.125f);
      }
    }
  }

  f32x4 oacc0[4], oacc1[4];
#pragma unroll
  for (int n = 0; n < 4; ++n) {
    oacc0[n] = (f32x4){0.f, 0.f, 0.f, 0.f};
    oacc1[n] = (f32x4){0.f, 0.f, 0.f, 0.f};
  }
  float m0[4] = {-INFINITY, -INFINITY, -INFINITY, -INFINITY};
  float l0[4] = {0.f, 0.f, 0.f, 0.f};
  float m1[4] = {-INFINITY, -INFINITY, -INFINITY, -INFINITY};
  float l1[4] = {0.f, 0.f, 0.f, 0.f};

  const int skey = tid >> 2, sc4 = tid & 3;

  for (int tt = 0; tt < ntt; ++tt) {
    if (tt) __syncthreads();
    {
      const _Float16* kp = qkv + (size_t)(bb * TT + tt * 64 + skey) * QS + hh * 64 + 1024;
      const _Float16* vp = kp + 1024;
#pragma unroll
      for (int ii = 0; ii < 4; ++ii) {
        const int d0 = sc4 * 4 + ii * 16;
        *(f16x4*)(Kl + swzA(skey, d0)) = *(const f16x4*)(kp + d0);
        const f16x4 vv = *(const f16x4*)(vp + d0);
        Vt[swzV(d0 + 0, skey)] = vv[0];
        Vt[swzV(d0 + 1, skey)] = vv[1];
        Vt[swzV(d0 + 2, skey)] = vv[2];
        Vt[swzV(d0 + 3, skey)] = vv[3];
      }
    }
    __syncthreads();
    attn_step(qf1, oacc1, m1, l1, Kl, Vt, Pl[wq], tt == qt1, wq, g, l16);
    if (tt <= qt0)
      attn_step(qf0, oacc0, m0, l0, Kl, Vt, Pl[wq], tt == qt0, wq, g, l16);
  }
#pragma unroll
  for (int n = 0; n < 4; ++n) {
#pragma unroll
    for (int reg = 0; reg < 4; ++reg) {
      const int r0 = qt0 * 64 + wq * 16 + g * 4 + reg;
      const int r1 = qt1 * 64 + wq * 16 + g * 4 + reg;
      seq_out[(size_t)(bb * TT + r0) * DD + hh * 64 + n * 16 + l16] = (_Float16)(oacc0[n][reg] / l0[reg]);
      seq_out[(size_t)(bb * TT + r1) * DD + hh * 64 + n * 16 + l16] = (_Float16)(oacc1[n][reg] / l1[reg]);
    }
  }
}

// ============ exterior products -> Jw, rd, gate (f16 mega input) ============
static __device__ __forceinline__ void ext6(const float* a, const float* b, float* L) {
  L[0] = a[0] * b[1] - a[1] * b[0];
  L[1] = a[0] * b[2] - a[2] * b[0];
  L[2] = a[0] * b[3] - a[3] * b[0];
  L[3] = a[1] * b[2] - a[2] * b[1];
  L[4] = a[1] * b[3] - a[3] * b[1];
  L[5] = a[2] * b[3] - a[3] * b[2];
  const float n = sqrtf(L[0]*L[0] + L[1]*L[1] + L[2]*L[2] + L[3]*L[3] + L[4]*L[4] + L[5]*L[5]);
  const float s = 1.f / fmaxf(n, 1e-12f);
#pragma unroll
  for (int i = 0; i < 6; ++i) L[i] *= s;
}

__global__ void lines_post(const _Float16* __restrict__ mega, float* __restrict__ jw,
                           float* __restrict__ rdv, float* __restrict__ gate) {
  const int idx = blockIdx.x * 256 + threadIdx.x;
  const int h = idx & 15;
  const int bt = idx >> 4;
  const int t = bt & 1023;
  const int b = bt >> 10;
  const _Float16* row = mega + (size_t)bt * QS + 3072;
  float w1[4] = {0.f, 0.f, 0.f, 0.f}, w2[4], r1[4], r2[4];
  if (t > 0) {
#pragma unroll
    for (int i = 0; i < 4; ++i) w1[i] = (float)row[-QS + h * 4 + i];
  }
#pragma unroll
  for (int i = 0; i < 4; ++i) {
    w2[i] = (float)row[64 + h * 4 + i];
    r1[i] = (float)row[128 + h * 4 + i];
    r2[i] = (float)row[192 + h * 4 + i];
  }
  const float gp = (float)row[256 + h];
  float wl[6], rl[6];
  ext6(w1, w2, wl);
  ext6(r1, r2, rl);
  const size_t o = ((size_t)(b * 16 + h) * 1024 + t) * 6;
  jw[o + 0] =  wl[5]; jw[o + 1] = -wl[4]; jw[o + 2] =  wl[3];
  jw[o + 3] =  wl[2]; jw[o + 4] = -wl[1]; jw[o + 5] =  wl[0];
#pragma unroll
  for (int i = 0; i < 6; ++i) rdv[o + i] = rl[i];
  gate[idx] = 1.f / (1.f + __expf(-gp));
}

// ============ chunk-parallel Gram scan ============
static __device__ __forceinline__ int midx(int i, int j) {
  return (i <= j) ? (i * (13 - i)) / 2 + (j - i) : (j * (13 - j)) / 2 + (i - j);
}

__global__ __launch_bounds__(64) void gram_scan(const float* __restrict__ jwv,
    const float* __restrict__ rdv, const float* __restrict__ decay_logits,
    const float* __restrict__ iter_mix, float* __restrict__ mem_score) {
  const int h = blockIdx.x & 15, b = blockIdx.x >> 4;
  const int lane = threadIdx.x;
  const float decay = 1.f / (1.f + __expf(-decay_logits[h]));
  const float alpha = 1.f / (1.f + __expf(-iter_mix[0]));
  __shared__ float sd[64 * 193];
  const size_t base = (size_t)(b * 16 + h) * 1024 * 6;
  for (int it = 0; it < 96; ++it) {
    const int idx = it * 64 + lane;
    const int t = idx / 6, i = idx - 6 * t;
    const int ld = t >> 4, s = t & 15;
    sd[ld * 193 + s * 6 + i] = jwv[base + idx];
    sd[ld * 193 + 96 + s * 6 + i] = rdv[base + idx];
  }
  __syncthreads();
  const float* seg = sd + lane * 193;

  float C[21];
#pragma unroll
  for (int e = 0; e < 21; ++e) C[e] = 0.f;
  for (int s = 0; s < 16; ++s) {
    float J[6], dJ[6];
#pragma unroll
    for (int i = 0; i < 6; ++i) { J[i] = seg[s * 6 + i]; dJ[i] = decay * J[i]; }
#pragma unroll
    for (int i = 0; i < 6; ++i)
#pragma unroll
      for (int j = i; j < 6; ++j)
        C[midx(i, j)] = decay * C[midx(i, j)] + dJ[i] * J[j];
  }
  const float d2 = decay * decay, d4 = d2 * d2, d8 = d4 * d4;
  float fk = d8 * d8;  // d^16
#pragma unroll
  for (int k = 0; k < 6; ++k) {
    const int off = 1 << k;
#pragma unroll
    for (int e = 0; e < 21; ++e) {
      const float u = __shfl(C[e], lane - off);
      if (lane >= off) C[e] += fk * u;
    }
    fk = fk * fk;
  }
  float M[21];
#pragma unroll
  for (int e = 0; e < 21; ++e) {
    const float u = __shfl(C[e], lane - 1);
    M[e] = (lane >= 1) ? u : 0.f;
  }
  float* msp = mem_score + (size_t)(b * 16 + h) * 1024 + lane * 16;
  for (int s = 0; s < 16; ++s) {
    float J[6], r[6];
#pragma unroll
    for (int i = 0; i < 6; ++i) { J[i] = seg[s * 6 + i]; r[i] = seg[96 + s * 6 + i]; }
    float rdM[6];
#pragma unroll
    for (int i = 0; i < 6; ++i) {
      float a = 0.f;
#pragma unroll
      for (int j = 0; j < 6; ++j) a += M[midx(i, j)] * r[j];
      rdM[i] = a;
    }
    float s1 = 0.f, s2 = 0.f;
#pragma unroll
    for (int i = 0; i < 6; ++i) { s1 += rdM[i] * r[i]; s2 += rdM[i] * rdM[i]; }
    msp[s] = (1.f - alpha) * s1 + alpha * s2;
    float dJ[6];
#pragma unroll
    for (int i = 0; i < 6; ++i) dJ[i] = decay * J[i];
#pragma unroll
    for (int i = 0; i < 6; ++i)
#pragma unroll
      for (int j = i; j < 6; ++j)
        M[midx(i, j)] = decay * M[midx(i, j)] + dJ[i] * J[j];
  }
}

// ============ combine (fused gated-mean): attnin = seq + gm*mv  (f16 out) ============
__global__ __launch_bounds__(256) void combine_kernel(const _Float16* __restrict__ seq,
    const _Float16* __restrict__ mega, const float* __restrict__ ms,
    const float* __restrict__ gate, const float* __restrict__ mem_scale,
    _Float16* __restrict__ outp) {
  const int bt = blockIdx.x;
  const int b = bt >> 10, t = bt & 1023;
  __shared__ float hterm[16];
  const int tid = threadIdx.x;
  if (tid < 16) {
    const float sc = ms[(size_t)(b * 16 + tid) * 1024 + t];
    const float gt = gate[(size_t)bt * 16 + tid];
    hterm[tid] = (1.f / (1.f + __expf(-sc * mem_scale[tid]))) * gt;
  }
  __syncthreads();
  float acc = 0.f;
#pragma unroll
  for (int h = 0; h < 16; ++h) acc += hterm[h];
  const float g = acc * (1.f / 16.f);
  const f16x4 s4 = *(const f16x4*)(seq + (size_t)bt * 1024 + tid * 4);
  const f16x4 m4 = *(const f16x4*)(mega + (size_t)bt * QS + 3584 + tid * 4);
  f16x4 o;
#pragma unroll
  for (int j = 0; j < 4; ++j) o[j] = (_Float16)((float)s4[j] + g * (float)m4[j]);
  *(f16x4*)(outp + (size_t)bt * 1024 + tid * 4) = o;
}

// ============ dst = src + bias  (pre-init for atomic split-K GEMMs) ============
__global__ void addb_init(const float* __restrict__ src, const float* __restrict__ bias,
                          float* __restrict__ dst) {
  const size_t i = (size_t)blockIdx.x * 256 + threadIdx.x;
  const int c4 = (int)(i & 255);
  const float4 s = ((const float4*)src)[i];
  const float4 b = ((const float4*)bias)[c4];
  float4 o;
  o.x = s.x + b.x; o.y = s.y + b.y; o.z = s.z + b.z; o.w = s.w + b.w;
  ((float4*)dst)[i] = o;
}

extern "C" void kernel_launch(void* const* d_in, const int* in_sizes, int n_in,
                              void* d_out, int out_size, void* d_ws, size_t ws_size,
                              hipStream_t stream) {
  (void)in_sizes; (void)n_in; (void)out_size; (void)ws_size;
  const float* x       = (const float*)d_in[0];
  const float* ln1_g   = (const float*)d_in[1];
  const float* ln1_b   = (const float*)d_in[2];
  const float* Wqkv    = (const float*)d_in[3];
  const float* bqkv    = (const float*)d_in[4];
  const float* W1w     = (const float*)d_in[5];
  const float* W2w     = (const float*)d_in[6];
  const float* W1r     = (const float*)d_in[7];
  const float* W2r     = (const float*)d_in[8];
  const float* Wmv     = (const float*)d_in[9];
  const float* bmv     = (const float*)d_in[10];
  const float* Wmg     = (const float*)d_in[11];
  const float* bmg     = (const float*)d_in[12];
  const float* mscale  = (const float*)d_in[13];
  const float* itermix = (const float*)d_in[14];
  const float* dlogits = (const float*)d_in[15];
  const float* Wout    = (const float*)d_in[16];
  const float* bout    = (const float*)d_in[17];
  const float* ln2_g   = (const float*)d_in[18];
  const float* ln2_b   = (const float*)d_in[19];
  const float* Wfc     = (const float*)d_in[20];
  const float* bfc     = (const float*)d_in[21];
  const float* Wproj   = (const float*)d_in[22];
  const float* bproj   = (const float*)d_in[23];
  float* out = (float*)d_out;
  float* ws = (float*)d_ws;

  const size_t M1 = 1u << 20;
  _Float16* h16    = (_Float16*)ws;                         // 0 .. 1M1 (2M f16)
  _Float16* WmT    = (_Float16*)(ws + 1 * M1);              // 1M1 .. 3.25M1
  float*    bm     = ws + 3407872;                          // 3.25M1, 4608
  float*    jw     = ws + 3538944;                          // 196608
  float*    rd     = ws + 3538944 + 196608;
  float*    gate   = ws + 3538944 + 393216;                 // 32768
  float*    ms     = ws + 3538944 + 425984;                 // 32768
  float*    y      = ws + 4 * M1;                           // 4M1 .. 6M1
  _Float16* mega   = (_Float16*)(ws + 6 * M1);              // 6M1 .. 10.5M1 (2048x4608 f16)
  _Float16* fc16   = (_Float16*)(ws + 6 * M1);              // reuses mega (dead by then)
  _Float16* seq16  = (_Float16*)(ws + 11010048);            // 10.5M1 .. 11.5M1
  _Float16* WoutT  = (_Float16*)(ws + 12058624);            // 11.5M1 .. 12M1
  _Float16* WfcT   = (_Float16*)(ws + 12 * M1);             // 12M1 .. 14M1
  _Float16* WprojT = (_Float16*)(ws + 14 * M1);             // 14M1 .. 16M1

  // ---- fused weight prep (1 dispatch) ----
  prep_all<<<3474, 256, 0, stream>>>(Wqkv, W1w, W2w, W1r, W2r, Wmg, Wmv, Wout, Wfc, Wproj,
                                     bqkv, bmg, bmv, WmT, WoutT, WfcT, WprojT, bm);

  // ---- block ----
  ln16<<<2048, 256, 0, stream>>>(x, ln1_g, ln1_b, h16);
  gemm_t16<<<576, 512, 0, stream>>>(h16, WmT, bm, nullptr, mega, 4608, 1024, 0, 36, 1, 32);
  attn_mfma<<<dim3(8, 16, 2), 256, 0, stream>>>(mega, seq16);
  lines_post<<<128, 256, 0, stream>>>(mega, jw, rd, gate);
  gram_scan<<<32, 64, 0, stream>>>(jw, rd, dlogits, itermix, ms);
  combine_kernel<<<2048, 256, 0, stream>>>(seq16, mega, ms, gate, mscale, h16);
  // y = attnin @ Wout + bout + x   (direct mode 3, no split-K, no pre-init)
  gemm_t16<<<128, 512, 0, stream>>>(h16, WoutT, bout, x, y, 1024, 1024, 0, 8, 3, 32);
  ln16<<<2048, 256, 0, stream>>>(y, ln2_g, ln2_b, h16);
  // fc = gelu(h2 @ Wfc + bfc), stored f16 (overwrites mega)
  gemm_t16<<<512, 512, 0, stream>>>(h16, WfcT, bfc, nullptr, fc16, 4096, 1024, 1, 32, 1, 32);
  // out = y + bproj + fc @ Wproj   (split-K=4 atomics into pre-initialized out)
  addb_init<<<2048, 256, 0, stream>>>(y, bproj, out);
  gemm_t16<<<dim3(128, 4), 512, 0, stream>>>(fc16, WprojT, nullptr, nullptr, out, 1024, 4096, 0, 8, 2, 32);
}